// Round 1
// baseline (299.365 us; speedup 1.0000x reference)
//
#include <hip/hip_runtime.h>

// OnLSTMCell fused pipeline for MI355X (gfx950).
// B=8192, input=1024, hidden=1024, level=64, d_in=2048.
// ws layout (bytes), total ~117 MB:
//   A_HI   @ 0          : u16[8192*2048]  (32 MB)   bf16(concat(input,h_prev))
//   A_LO   @ 33554432   : u16[8192*2048]  (32 MB)   bf16 residual (level path precision)
//   W_HI   @ 67108864   : u16[4224*2048]  (16.5 MB) rows 0..4095 gate-interleaved (n=j*4+gate), 4096..4223 = W_level
//   WLEV_LO@ 84410368   : u16[128*2048]   (0.5 MB)
//   PART   @ 84934656   : f32[8][8192][128] (32 MB) split-K partials of level GEMM
//   IH     @ 118489088  : f32[8192*64]    (2 MB)
//   FH     @ 120586240  : f32[8192*64]    (2 MB)

typedef unsigned short u16;
typedef __attribute__((ext_vector_type(8))) short bf16x8;
typedef __attribute__((ext_vector_type(8))) short s8v;
typedef __attribute__((ext_vector_type(4))) float f32x4;
typedef __attribute__((ext_vector_type(4))) float v4f;

#define GLDS(g, l) __builtin_amdgcn_global_load_lds(                      \
    (const __attribute__((address_space(1))) void*)(g),                   \
    (__attribute__((address_space(3))) void*)(l), 16, 0, 0)

__device__ __forceinline__ u16 f2bf(float x) {
  unsigned u = __builtin_bit_cast(unsigned, x);
  u += 0x7FFFu + ((u >> 16) & 1u);
  return (u16)(u >> 16);
}
__device__ __forceinline__ float bf2f(u16 h) {
  unsigned u = ((unsigned)h) << 16;
  return __builtin_bit_cast(float, u);
}
__device__ __forceinline__ float fsig(float x) { return 1.0f / (1.0f + __expf(-x)); }
// robust tanh: no inf/inf NaN at |x| large
__device__ __forceinline__ float ftanhf(float x) { float e = __expf(2.0f * x); return 1.0f - 2.0f / (e + 1.0f); }

// ---------------------------------------------------------------- convert ---
__global__ __launch_bounds__(256) void k_convert(
    const float* __restrict__ inp, const float* __restrict__ hprev,
    const float* __restrict__ wl, const float* __restrict__ wlev,
    u16* __restrict__ Ahi, u16* __restrict__ Alo,
    u16* __restrict__ Whi, u16* __restrict__ Wlo)
{
  const int GA = (8192 * 2048) / 8;   // 2097152
  const int GW = (4224 * 2048) / 8;   // 1081344
  for (int gi = blockIdx.x * 256 + threadIdx.x; gi < GA + GW; gi += gridDim.x * 256) {
    if (gi < GA) {
      int e = gi << 3; int row = e >> 11, col = e & 2047;
      const float* src = (col < 1024) ? (inp + row * 1024 + col)
                                      : (hprev + row * 1024 + (col - 1024));
      v4f a = *(const v4f*)src, b = *(const v4f*)(src + 4);
      float vv[8] = {a.x, a.y, a.z, a.w, b.x, b.y, b.z, b.w};
      s8v hi, lo;
#pragma unroll
      for (int j = 0; j < 8; ++j) {
        u16 h = f2bf(vv[j]);
        hi[j] = (short)h;
        lo[j] = (short)f2bf(vv[j] - bf2f(h));
      }
      *(s8v*)(Ahi + e) = hi;
      *(s8v*)(Alo + e) = lo;
    } else {
      int e = (gi - GA) << 3; int n = e >> 11, k = e & 2047;
      const float* src;
      if (n < 4096) { int j = n >> 2, g = n & 3; src = wl + (size_t)((g << 10) | j) * 2048 + k; }
      else          { src = wlev + (size_t)(n - 4096) * 2048 + k; }
      v4f a = *(const v4f*)src, b = *(const v4f*)(src + 4);
      float vv[8] = {a.x, a.y, a.z, a.w, b.x, b.y, b.z, b.w};
      s8v hi, lo;
#pragma unroll
      for (int j = 0; j < 8; ++j) {
        u16 h = f2bf(vv[j]);
        hi[j] = (short)h;
        lo[j] = (short)f2bf(vv[j] - bf2f(h));
      }
      *(s8v*)(Whi + e) = hi;
      if (n >= 4096) *(s8v*)(Wlo + (size_t)(n - 4096) * 2048 + k) = lo;
    }
  }
}

// ----------------------------------------------- level GEMM (split-bf16) ---
// grid (64, 8): blockIdx.x = row tile (128 rows), blockIdx.y = K-split s.
__global__ __launch_bounds__(256) void k_gemm_level(
    const u16* __restrict__ Ahi, const u16* __restrict__ Alo,
    const u16* __restrict__ Whi, const u16* __restrict__ Wlo,
    float* __restrict__ part)
{
  __shared__ __align__(16) u16 smem[4 * 8192];   // 64 KB: Ah | Al | Bh | Bl
  u16 *Ah = smem, *Al = smem + 8192, *Bh = smem + 16384, *Bl = smem + 24576;
  const int tid = threadIdx.x, lane = tid & 63, wid = tid >> 6;
  const int wm = wid >> 1, wn = wid & 1;
  const int rm = blockIdx.x, s = blockIdx.y;
  const int lrow = lane >> 3, lcolE = (lane & 7) << 3;
  const int c16 = lane & 15, r16 = lane >> 4;
  f32x4 acc[4][4] = {};
  const u16* aBaseH = Ahi + (size_t)(rm << 7) * 2048;
  const u16* aBaseL = Alo + (size_t)(rm << 7) * 2048;
  const u16* bBaseH = Whi + (size_t)4096 * 2048;

  for (int kt = 0; kt < 4; ++kt) {
    const int k0 = (s << 8) + (kt << 6);
#pragma unroll
    for (int q = 0; q < 4; ++q) {
      const int ca = (wid << 2) + q;
      size_t roff = (size_t)((ca << 3) + lrow) * 2048 + k0 + lcolE;
      GLDS(aBaseH + roff, Ah + (ca << 9));
      GLDS(aBaseL + roff, Al + (ca << 9));
      GLDS(bBaseH + roff, Bh + (ca << 9));
      GLDS(Wlo + roff,    Bl + (ca << 9));
    }
    __syncthreads();
#pragma unroll
    for (int ks = 0; ks < 2; ++ks) {
      bf16x8 ah[4], al[4];
#pragma unroll
      for (int i = 0; i < 4; ++i) {
        int off = ((wm << 6) + (i << 4) + c16) * 64 + (ks << 5) + (r16 << 3);
        ah[i] = *(const bf16x8*)(Ah + off);
        al[i] = *(const bf16x8*)(Al + off);
      }
#pragma unroll
      for (int j = 0; j < 4; ++j) {
        int off = ((wn << 6) + (j << 4) + c16) * 64 + (ks << 5) + (r16 << 3);
        bf16x8 bh = *(const bf16x8*)(Bh + off);
        bf16x8 bl = *(const bf16x8*)(Bl + off);
#pragma unroll
        for (int i = 0; i < 4; ++i) {
          acc[i][j] = __builtin_amdgcn_mfma_f32_16x16x32_bf16(ah[i], bh, acc[i][j], 0, 0, 0);
          acc[i][j] = __builtin_amdgcn_mfma_f32_16x16x32_bf16(al[i], bh, acc[i][j], 0, 0, 0);
          acc[i][j] = __builtin_amdgcn_mfma_f32_16x16x32_bf16(ah[i], bl, acc[i][j], 0, 0, 0);
        }
      }
    }
    __syncthreads();
  }
#pragma unroll
  for (int mi = 0; mi < 4; ++mi)
#pragma unroll
    for (int ni = 0; ni < 4; ++ni)
#pragma unroll
      for (int r = 0; r < 4; ++r) {
        int ml = (wm << 6) + (mi << 4) + (r16 << 2) + r;
        int nl = (wn << 6) + (ni << 4) + c16;
        part[(size_t)((s << 13) + (rm << 7) + ml) * 128 + nl] = acc[mi][ni][r];
      }
}

// ------------------------------------------- softmax + cumsums (per row) ---
// grid 2048 x 256: one wave per row.
__global__ __launch_bounds__(256) void k_softmax(
    const float* __restrict__ part, float* __restrict__ ih, float* __restrict__ fh)
{
  const int tid = threadIdx.x, lane = tid & 63, w = tid >> 6;
  const int row = blockIdx.x * 4 + w;
  float vi = 0.f, vf = 0.f;
#pragma unroll
  for (int s = 0; s < 8; ++s) {
    vi += part[(size_t)((s << 13) + row) * 128 + lane];
    vf += part[(size_t)((s << 13) + row) * 128 + 64 + lane];
  }
  float mi = vi, mf = vf;
#pragma unroll
  for (int d = 1; d < 64; d <<= 1) {
    mi = fmaxf(mi, __shfl_xor(mi, d, 64));
    mf = fmaxf(mf, __shfl_xor(mf, d, 64));
  }
  float ei = __expf(vi - mi), ef = __expf(vf - mf);
  float si = ei, sf = ef;
#pragma unroll
  for (int d = 1; d < 64; d <<= 1) {
    si += __shfl_xor(si, d, 64);
    sf += __shfl_xor(sf, d, 64);
  }
  float pi = ei / si, pf = ef / sf;
  float ci = pi, cf = pf;
#pragma unroll
  for (int d = 1; d < 64; d <<= 1) {
    float t = __shfl_up(ci, d, 64); if (lane >= d) ci += t;
    float u = __shfl_up(cf, d, 64); if (lane >= d) cf += u;
  }
  // f_h = forward inclusive cumsum; i_h = reverse (suffix) inclusive cumsum
  ih[(row << 6) + lane] = 1.0f - (ci - pi);
  fh[(row << 6) + lane] = cf;
}

// -------------------------------------- main gates GEMM + fused epilogue ---
// grid 2048: rm = bx>>5 (64 row tiles of 128), cm = bx&31 (32 col tiles of 128
// interleaved gate-cols = 32 hidden units each). m97 structure: BK=64,
// global_load_lds(16B), 2 barriers/K-step, 4 waves, acc 4x4 of 16x16x32 bf16.
__global__ __launch_bounds__(256) void k_gemm_main(
    const u16* __restrict__ Ab, const u16* __restrict__ Wb,
    const float* __restrict__ cprev, const float* __restrict__ ihp,
    const float* __restrict__ fhp, float* __restrict__ out)
{
  __shared__ __align__(16) u16 smem[2 * 8192];   // 32 KB: As | Bs, reused as f32 epi[128][64]
  u16* As = smem; u16* Bs = smem + 8192;
  const int tid = threadIdx.x, lane = tid & 63, wid = tid >> 6;
  const int wm = wid >> 1, wn = wid & 1;
  const int rm = blockIdx.x >> 5, cm = blockIdx.x & 31;
  const int lrow = lane >> 3, lcolE = (lane & 7) << 3;
  const int c16 = lane & 15, r16 = lane >> 4;

  f32x4 acc[4][4] = {};
  const u16* aBase = Ab + (size_t)(rm << 7) * 2048;
  const u16* bBase = Wb + (size_t)(cm << 7) * 2048;

  for (int kt = 0; kt < 32; ++kt) {
    const int k0 = kt << 6;
#pragma unroll
    for (int q = 0; q < 4; ++q) {
      const int ca = (wid << 2) + q;
      GLDS(aBase + (size_t)((ca << 3) + lrow) * 2048 + k0 + lcolE, As + (ca << 9));
      GLDS(bBase + (size_t)((ca << 3) + lrow) * 2048 + k0 + lcolE, Bs + (ca << 9));
    }
    __syncthreads();
#pragma unroll
    for (int ks = 0; ks < 2; ++ks) {
      bf16x8 af[4], bfr[4];
#pragma unroll
      for (int i = 0; i < 4; ++i) {
        af[i]  = *(const bf16x8*)(As + ((wm << 6) + (i << 4) + c16) * 64 + (ks << 5) + (r16 << 3));
        bfr[i] = *(const bf16x8*)(Bs + ((wn << 6) + (i << 4) + c16) * 64 + (ks << 5) + (r16 << 3));
      }
#pragma unroll
      for (int i = 0; i < 4; ++i)
#pragma unroll
        for (int j = 0; j < 4; ++j)
          acc[i][j] = __builtin_amdgcn_mfma_f32_16x16x32_bf16(af[i], bfr[j], acc[i][j], 0, 0, 0);
    }
    __syncthreads();
  }

  // Fused ON-LSTM epilogue. Two half-passes (cols 0..63 then 64..127) so the
  // f32 staging buffer fits the 32 KB LDS union. gate = col&3 = lane&3
  // (0=i,1=f,2=o,3=g since col tiles are multiples of 4).
  float* epi = (float*)smem;   // [128][64] f32
  for (int p = 0; p < 2; ++p) {
    if (wn == p) {
#pragma unroll
      for (int mi = 0; mi < 4; ++mi)
#pragma unroll
        for (int ni = 0; ni < 4; ++ni)
#pragma unroll
          for (int r = 0; r < 4; ++r) {
            int rowl = (wm << 6) + (mi << 4) + (r16 << 2) + r;
            int coll = (ni << 4) + c16;
            float v = acc[mi][ni][r];
            v = ((lane & 3) == 3) ? ftanhf(v) : fsig(v);
            epi[rowl * 64 + coll] = v;
          }
    }
    __syncthreads();
#pragma unroll
    for (int e = 0; e < 8; ++e) {
      int idx = (e << 8) + tid;
      int m = idx >> 4, jl = idx & 15;
      v4f v = *(const v4f*)(epi + m * 64 + (jl << 2));   // i,f,o,g (activated)
      int rowg = (rm << 7) + m;
      int jg = (cm << 5) + (p << 4) + jl;
      float cp = cprev[rowg * 1024 + jg];
      int lv = jg >> 4;                                   // repeat factor 16
      float vih = ihp[(rowg << 6) + lv], vfh = fhp[(rowg << 6) + lv];
      float iv = v.x, fv = v.y, ov = v.z, gv = v.w;
      float wq = vih * vfh;
      float c = wq * (fv * cp + iv * gv) + (vfh - wq) * cp + (vih - wq) * gv;
      float h = ov * ftanhf(c);
      out[rowg * 1024 + jg] = h;
      out[8388608 + rowg * 1024 + jg] = c;
    }
    __syncthreads();
  }
}

// -------------------------------------------------------------- launcher ---
extern "C" void kernel_launch(void* const* d_in, const int* in_sizes, int n_in,
                              void* d_out, int out_size, void* d_ws, size_t ws_size,
                              hipStream_t stream) {
  (void)in_sizes; (void)n_in; (void)out_size; (void)ws_size;
  const float* inp   = (const float*)d_in[0];
  const float* hprev = (const float*)d_in[1];
  const float* cprev = (const float*)d_in[2];
  const float* wl    = (const float*)d_in[3];
  const float* wlev  = (const float*)d_in[4];
  float* out = (float*)d_out;
  char* ws = (char*)d_ws;

  u16* Ahi  = (u16*)(ws);
  u16* Alo  = (u16*)(ws + 33554432);
  u16* Whi  = (u16*)(ws + 67108864);
  u16* Wlo  = (u16*)(ws + 84410368);
  float* part = (float*)(ws + 84934656);
  float* ih   = (float*)(ws + 118489088);
  float* fh   = (float*)(ws + 120586240);

  k_convert<<<dim3(2048), dim3(256), 0, stream>>>(inp, hprev, wl, wlev, Ahi, Alo, Whi, Wlo);
  k_gemm_level<<<dim3(64, 8), dim3(256), 0, stream>>>(Ahi, Alo, Whi, Wlo, part);
  k_softmax<<<dim3(2048), dim3(256), 0, stream>>>(part, ih, fh);
  k_gemm_main<<<dim3(2048), dim3(256), 0, stream>>>(Ahi, Whi, cprev, ih, fh, out);
}

// Round 2
// 261.260 us; speedup vs baseline: 1.1459x; 1.1459x over previous
//
#include <hip/hip_runtime.h>

// OnLSTMCell fused pipeline for MI355X (gfx950).
// B=8192, input=1024, hidden=1024, level=64, d_in=2048.
// ws layout (bytes), total ~117 MB:
//   A_HI   @ 0          : u16[8192*2048]  (32 MB)   bf16(concat(input,h_prev))
//   A_LO   @ 33554432   : u16[8192*2048]  (32 MB)   bf16 residual (level path precision)
//   W_HI   @ 67108864   : u16[4224*2048]  (16.5 MB) rows 0..4095 gate-interleaved (n=j*4+gate), 4096..4223 = W_level
//   WLEV_LO@ 84410368   : u16[128*2048]   (0.5 MB)
//   PART   @ 84934656   : f32[8][8192][128] (32 MB) split-K partials of level GEMM
//   IH     @ 118489088  : f32[8192*64]    (2 MB)
//   FH     @ 120586240  : f32[8192*64]    (2 MB)

typedef unsigned short u16;
typedef __attribute__((ext_vector_type(8))) short bf16x8;
typedef __attribute__((ext_vector_type(8))) short s8v;
typedef __attribute__((ext_vector_type(4))) float f32x4;
typedef __attribute__((ext_vector_type(4))) float v4f;

#define GLDS(g, l) __builtin_amdgcn_global_load_lds(                      \
    (const __attribute__((address_space(1))) void*)(g),                   \
    (__attribute__((address_space(3))) void*)(l), 16, 0, 0)

__device__ __forceinline__ u16 f2bf(float x) {
  unsigned u = __builtin_bit_cast(unsigned, x);
  u += 0x7FFFu + ((u >> 16) & 1u);
  return (u16)(u >> 16);
}
__device__ __forceinline__ float bf2f(u16 h) {
  unsigned u = ((unsigned)h) << 16;
  return __builtin_bit_cast(float, u);
}
__device__ __forceinline__ float fsig(float x) { return 1.0f / (1.0f + __expf(-x)); }
__device__ __forceinline__ float ftanhf(float x) { float e = __expf(2.0f * x); return 1.0f - 2.0f / (e + 1.0f); }

// ---------------------------------------------------------------- convert ---
__global__ __launch_bounds__(256) void k_convert(
    const float* __restrict__ inp, const float* __restrict__ hprev,
    const float* __restrict__ wl, const float* __restrict__ wlev,
    u16* __restrict__ Ahi, u16* __restrict__ Alo,
    u16* __restrict__ Whi, u16* __restrict__ Wlo)
{
  const int GA = (8192 * 2048) / 8;
  const int GW = (4224 * 2048) / 8;
  for (int gi = blockIdx.x * 256 + threadIdx.x; gi < GA + GW; gi += gridDim.x * 256) {
    if (gi < GA) {
      int e = gi << 3; int row = e >> 11, col = e & 2047;
      const float* src = (col < 1024) ? (inp + row * 1024 + col)
                                      : (hprev + row * 1024 + (col - 1024));
      v4f a = *(const v4f*)src, b = *(const v4f*)(src + 4);
      float vv[8] = {a.x, a.y, a.z, a.w, b.x, b.y, b.z, b.w};
      s8v hi, lo;
#pragma unroll
      for (int j = 0; j < 8; ++j) {
        u16 h = f2bf(vv[j]);
        hi[j] = (short)h;
        lo[j] = (short)f2bf(vv[j] - bf2f(h));
      }
      *(s8v*)(Ahi + e) = hi;
      *(s8v*)(Alo + e) = lo;
    } else {
      int e = (gi - GA) << 3; int n = e >> 11, k = e & 2047;
      const float* src;
      if (n < 4096) { int j = n >> 2, g = n & 3; src = wl + (size_t)((g << 10) | j) * 2048 + k; }
      else          { src = wlev + (size_t)(n - 4096) * 2048 + k; }
      v4f a = *(const v4f*)src, b = *(const v4f*)(src + 4);
      float vv[8] = {a.x, a.y, a.z, a.w, b.x, b.y, b.z, b.w};
      s8v hi, lo;
#pragma unroll
      for (int j = 0; j < 8; ++j) {
        u16 h = f2bf(vv[j]);
        hi[j] = (short)h;
        lo[j] = (short)f2bf(vv[j] - bf2f(h));
      }
      *(s8v*)(Whi + e) = hi;
      if (n >= 4096) *(s8v*)(Wlo + (size_t)(n - 4096) * 2048 + k) = lo;
    }
  }
}

// ----------------------------------------------- level GEMM (split-bf16) ---
__global__ __launch_bounds__(256) void k_gemm_level(
    const u16* __restrict__ Ahi, const u16* __restrict__ Alo,
    const u16* __restrict__ Whi, const u16* __restrict__ Wlo,
    float* __restrict__ part)
{
  __shared__ __align__(16) u16 smem[4 * 8192];
  u16 *Ah = smem, *Al = smem + 8192, *Bh = smem + 16384, *Bl = smem + 24576;
  const int tid = threadIdx.x, lane = tid & 63, wid = tid >> 6;
  const int wm = wid >> 1, wn = wid & 1;
  const int rm = blockIdx.x, s = blockIdx.y;
  const int lrow = lane >> 3, lcolE = (lane & 7) << 3;
  const int c16 = lane & 15, r16 = lane >> 4;
  f32x4 acc[4][4] = {};
  const u16* aBaseH = Ahi + (size_t)(rm << 7) * 2048;
  const u16* aBaseL = Alo + (size_t)(rm << 7) * 2048;
  const u16* bBaseH = Whi + (size_t)4096 * 2048;

  for (int kt = 0; kt < 4; ++kt) {
    const int k0 = (s << 8) + (kt << 6);
#pragma unroll
    for (int q = 0; q < 4; ++q) {
      const int ca = (wid << 2) + q;
      size_t roff = (size_t)((ca << 3) + lrow) * 2048 + k0 + lcolE;
      GLDS(aBaseH + roff, Ah + (ca << 9));
      GLDS(aBaseL + roff, Al + (ca << 9));
      GLDS(bBaseH + roff, Bh + (ca << 9));
      GLDS(Wlo + roff,    Bl + (ca << 9));
    }
    __syncthreads();
#pragma unroll
    for (int ks = 0; ks < 2; ++ks) {
      bf16x8 ah[4], al[4];
#pragma unroll
      for (int i = 0; i < 4; ++i) {
        int off = ((wm << 6) + (i << 4) + c16) * 64 + (ks << 5) + (r16 << 3);
        ah[i] = *(const bf16x8*)(Ah + off);
        al[i] = *(const bf16x8*)(Al + off);
      }
#pragma unroll
      for (int j = 0; j < 4; ++j) {
        int off = ((wn << 6) + (j << 4) + c16) * 64 + (ks << 5) + (r16 << 3);
        bf16x8 bh = *(const bf16x8*)(Bh + off);
        bf16x8 bl = *(const bf16x8*)(Bl + off);
#pragma unroll
        for (int i = 0; i < 4; ++i) {
          acc[i][j] = __builtin_amdgcn_mfma_f32_16x16x32_bf16(ah[i], bh, acc[i][j], 0, 0, 0);
          acc[i][j] = __builtin_amdgcn_mfma_f32_16x16x32_bf16(al[i], bh, acc[i][j], 0, 0, 0);
          acc[i][j] = __builtin_amdgcn_mfma_f32_16x16x32_bf16(ah[i], bl, acc[i][j], 0, 0, 0);
        }
      }
    }
    __syncthreads();
  }
#pragma unroll
  for (int mi = 0; mi < 4; ++mi)
#pragma unroll
    for (int ni = 0; ni < 4; ++ni)
#pragma unroll
      for (int r = 0; r < 4; ++r) {
        int ml = (wm << 6) + (mi << 4) + (r16 << 2) + r;
        int nl = (wn << 6) + (ni << 4) + c16;
        part[(size_t)((s << 13) + (rm << 7) + ml) * 128 + nl] = acc[mi][ni][r];
      }
}

// ------------------------------------------- softmax + cumsums (per row) ---
__global__ __launch_bounds__(256) void k_softmax(
    const float* __restrict__ part, float* __restrict__ ih, float* __restrict__ fh)
{
  const int tid = threadIdx.x, lane = tid & 63, w = tid >> 6;
  const int row = blockIdx.x * 4 + w;
  float vi = 0.f, vf = 0.f;
#pragma unroll
  for (int s = 0; s < 8; ++s) {
    vi += part[(size_t)((s << 13) + row) * 128 + lane];
    vf += part[(size_t)((s << 13) + row) * 128 + 64 + lane];
  }
  float mi = vi, mf = vf;
#pragma unroll
  for (int d = 1; d < 64; d <<= 1) {
    mi = fmaxf(mi, __shfl_xor(mi, d, 64));
    mf = fmaxf(mf, __shfl_xor(mf, d, 64));
  }
  float ei = __expf(vi - mi), ef = __expf(vf - mf);
  float si = ei, sf = ef;
#pragma unroll
  for (int d = 1; d < 64; d <<= 1) {
    si += __shfl_xor(si, d, 64);
    sf += __shfl_xor(sf, d, 64);
  }
  float pi = ei / si, pf = ef / sf;
  float ci = pi, cf = pf;
#pragma unroll
  for (int d = 1; d < 64; d <<= 1) {
    float t = __shfl_up(ci, d, 64); if (lane >= d) ci += t;
    float u = __shfl_up(cf, d, 64); if (lane >= d) cf += u;
  }
  ih[(row << 6) + lane] = 1.0f - (ci - pi);
  fh[(row << 6) + lane] = cf;
}

// -------------------------------------- main gates GEMM + fused epilogue ---
// 256x256 tile, BK=32, 512 threads (8 waves 2Mx4N), per-wave 128x64 output.
// Triple-buffered LDS (3 x 32KB), counted vmcnt(4) (never 0 mid-loop), raw
// s_barrier (1 per K-tile), T2 both-sides swizzle (slot ^= row&3), T5 setprio.
__global__ __launch_bounds__(512, 2) void k_gemm_main(
    const u16* __restrict__ Ab, const u16* __restrict__ Wb,
    const float* __restrict__ cprev, const float* __restrict__ ihp,
    const float* __restrict__ fhp, float* __restrict__ out)
{
  __shared__ __align__(16) u16 smem[3 * 16384];   // 96 KB; epilogue reuses 64 KB as f32[256][64]
  const int tid = threadIdx.x, lane = tid & 63, wid = tid >> 6;
  const int wm = wid >> 2, wn = wid & 3;          // 2 x 4 wave grid
  const int c16 = lane & 15, r16 = lane >> 4;

  // bijective XCD swizzle (nwg=512, 512%8==0)
  const int bx = blockIdx.x;
  const int nb = (bx & 7) * 64 + (bx >> 3);
  const int rm = nb >> 4, cm = nb & 15;           // 32 row tiles x 16 col tiles

  // --- staging source pointers (inverse-swizzled global, linear LDS dest) ---
  // LDS tile layout: [256 rows][4 slots of 8 bf16]; slot sl holds k-block sl^(row&3).
  const int sr = tid >> 2;                         // row within 128-row group
  const int sl = tid & 3;                          // 16B slot
  const int ss = ((sl ^ (sr & 3)) << 3);           // element offset (inverse swizzle)
  const u16* pa0 = Ab + (size_t)(rm * 256 + sr      ) * 2048 + ss;
  const u16* pa1 = Ab + (size_t)(rm * 256 + 128 + sr) * 2048 + ss;
  const u16* pb0 = Wb + (size_t)(cm * 256 + sr      ) * 2048 + ss;
  const u16* pb1 = Wb + (size_t)(cm * 256 + 128 + sr) * 2048 + ss;
  char* const ldsW = (char*)smem + (wid << 10);    // wave-uniform wave segment

  // --- ds_read offsets (swizzled): frag row r, slot r16 ^ (r&3); (r&3)==(c16&3)
  const int aoff = (wm * 128 + c16) * 32 + ((r16 ^ (c16 & 3)) << 3);  // + i*512
  const int boff = (wn * 64  + c16) * 32 + ((r16 ^ (c16 & 3)) << 3);  // + j*512

  f32x4 acc[8][4] = {};

#define STAGE(kt, b) do {                                              \
    char* d_ = ldsW + ((b) << 15);                                     \
    const int k0_ = (kt) << 5;                                         \
    GLDS(pa0 + k0_, d_);                                               \
    GLDS(pa1 + k0_, d_ + 8192);                                        \
    GLDS(pb0 + k0_, d_ + 16384);                                       \
    GLDS(pb1 + k0_, d_ + 24576);                                       \
  } while (0)

  // prologue: tiles 0,1 staged; tile 0 complete, tile 1 in flight.
  STAGE(0, 0);
  STAGE(1, 1);
  asm volatile("s_waitcnt vmcnt(4)" ::: "memory");
  __builtin_amdgcn_s_barrier();

  int cur = 0, st = 2;
  for (int t = 0; t < 64; ++t) {
    if (t + 2 < 64) STAGE(t + 2, st);
    const u16* bufp = smem + (cur << 13) * 2;      // cur*16384 elements
    bf16x8 af[8], bq[4];
#pragma unroll
    for (int i = 0; i < 8; ++i) af[i] = *(const bf16x8*)(bufp + aoff + i * 512);
#pragma unroll
    for (int j = 0; j < 4; ++j) bq[j] = *(const bf16x8*)(bufp + 8192 + boff + j * 512);
    __builtin_amdgcn_s_setprio(1);
#pragma unroll
    for (int i = 0; i < 8; ++i)
#pragma unroll
      for (int j = 0; j < 4; ++j)
        acc[i][j] = __builtin_amdgcn_mfma_f32_16x16x32_bf16(af[i], bq[j], acc[i][j], 0, 0, 0);
    __builtin_amdgcn_s_setprio(0);
    if (t + 2 < 64) { asm volatile("s_waitcnt vmcnt(4)" ::: "memory"); }
    else            { asm volatile("s_waitcnt vmcnt(0)" ::: "memory"); }
    __builtin_amdgcn_s_barrier();
    cur = (cur == 2) ? 0 : cur + 1;
    st  = (st  == 2) ? 0 : st  + 1;
  }
#undef STAGE

  // ---- fused ON-LSTM epilogue: 4 passes (one per wn), epi = f32[256][64] ----
  float* epi = (float*)smem;
  for (int p = 0; p < 4; ++p) {
    if (wn == p) {
#pragma unroll
      for (int i = 0; i < 8; ++i)
#pragma unroll
        for (int j = 0; j < 4; ++j)
#pragma unroll
          for (int r = 0; r < 4; ++r) {
            int rowl = wm * 128 + i * 16 + r16 * 4 + r;
            int coll = j * 16 + c16;
            float v = acc[i][j][r];
            v = ((c16 & 3) == 3) ? ftanhf(v) : fsig(v);
            epi[rowl * 64 + coll] = v;
          }
    }
    __syncthreads();
#pragma unroll
    for (int e = 0; e < 8; ++e) {
      int idx = (e << 9) + tid;
      int m = idx >> 4, jl = idx & 15;
      v4f v = *(const v4f*)(epi + m * 64 + (jl << 2));   // i,f,o,g (activated)
      int rowg = rm * 256 + m;
      int jg = cm * 64 + p * 16 + jl;                    // hidden index
      float cp = cprev[rowg * 1024 + jg];
      int lv = jg >> 4;
      float vih = ihp[(rowg << 6) + lv], vfh = fhp[(rowg << 6) + lv];
      float iv = v.x, fv = v.y, ov = v.z, gv = v.w;
      float wq = vih * vfh;
      float c = wq * (fv * cp + iv * gv) + (vfh - wq) * cp + (vih - wq) * gv;
      float h = ov * ftanhf(c);
      out[rowg * 1024 + jg] = h;
      out[8388608 + rowg * 1024 + jg] = c;
    }
    __syncthreads();
  }
}

// -------------------------------------------------------------- launcher ---
extern "C" void kernel_launch(void* const* d_in, const int* in_sizes, int n_in,
                              void* d_out, int out_size, void* d_ws, size_t ws_size,
                              hipStream_t stream) {
  (void)in_sizes; (void)n_in; (void)out_size; (void)ws_size;
  const float* inp   = (const float*)d_in[0];
  const float* hprev = (const float*)d_in[1];
  const float* cprev = (const float*)d_in[2];
  const float* wl    = (const float*)d_in[3];
  const float* wlev  = (const float*)d_in[4];
  float* out = (float*)d_out;
  char* ws = (char*)d_ws;

  u16* Ahi  = (u16*)(ws);
  u16* Alo  = (u16*)(ws + 33554432);
  u16* Whi  = (u16*)(ws + 67108864);
  u16* Wlo  = (u16*)(ws + 84410368);
  float* part = (float*)(ws + 84934656);
  float* ih   = (float*)(ws + 118489088);
  float* fh   = (float*)(ws + 120586240);

  k_convert<<<dim3(2048), dim3(256), 0, stream>>>(inp, hprev, wl, wlev, Ahi, Alo, Whi, Wlo);
  k_gemm_level<<<dim3(64, 8), dim3(256), 0, stream>>>(Ahi, Alo, Whi, Wlo, part);
  k_softmax<<<dim3(2048), dim3(256), 0, stream>>>(part, ih, fh);
  k_gemm_main<<<dim3(512), dim3(512), 0, stream>>>(Ahi, Whi, cprev, ih, fh, out);
}

// Round 3
// 258.099 us; speedup vs baseline: 1.1599x; 1.0122x over previous
//
#include <hip/hip_runtime.h>

// OnLSTMCell fused pipeline for MI355X (gfx950).
// B=8192, input=1024, hidden=1024, level=64, d_in=2048.
// ws layout (bytes), total ~117 MB:
//   A_HI   @ 0          : u16[8192*2048]  (32 MB)   bf16(concat(input,h_prev))
//   A_LO   @ 33554432   : u16[8192*2048]  (32 MB)   bf16 residual (level path precision)
//   W_HI   @ 67108864   : u16[4224*2048]  (16.5 MB) rows 0..4095 gate-interleaved (n=j*4+gate), 4096..4223 = W_level
//   WLEV_LO@ 84410368   : u16[128*2048]   (0.5 MB)
//   PART   @ 84934656   : f32[8][8192][128] (32 MB) split-K partials of level GEMM
//   IH     @ 118489088  : f32[8192*64]    (2 MB)
//   FH     @ 120586240  : f32[8192*64]    (2 MB)

typedef unsigned short u16;
typedef __attribute__((ext_vector_type(8))) short bf16x8;
typedef __attribute__((ext_vector_type(8))) short s8v;
typedef __attribute__((ext_vector_type(4))) float f32x4;
typedef __attribute__((ext_vector_type(4))) float v4f;

#define GLDS(g, l) __builtin_amdgcn_global_load_lds(                      \
    (const __attribute__((address_space(1))) void*)(g),                   \
    (__attribute__((address_space(3))) void*)(l), 16, 0, 0)

__device__ __forceinline__ u16 f2bf(float x) {
  unsigned u = __builtin_bit_cast(unsigned, x);
  u += 0x7FFFu + ((u >> 16) & 1u);
  return (u16)(u >> 16);
}
__device__ __forceinline__ float bf2f(u16 h) {
  unsigned u = ((unsigned)h) << 16;
  return __builtin_bit_cast(float, u);
}
__device__ __forceinline__ float fsig(float x) { return 1.0f / (1.0f + __expf(-x)); }
__device__ __forceinline__ float ftanhf(float x) { float e = __expf(2.0f * x); return 1.0f - 2.0f / (e + 1.0f); }

// ---------------------------------------------------------------- convert ---
__global__ __launch_bounds__(256) void k_convert(
    const float* __restrict__ inp, const float* __restrict__ hprev,
    const float* __restrict__ wl, const float* __restrict__ wlev,
    u16* __restrict__ Ahi, u16* __restrict__ Alo,
    u16* __restrict__ Whi, u16* __restrict__ Wlo)
{
  const int GA = (8192 * 2048) / 8;
  const int GW = (4224 * 2048) / 8;
  for (int gi = blockIdx.x * 256 + threadIdx.x; gi < GA + GW; gi += gridDim.x * 256) {
    if (gi < GA) {
      int e = gi << 3; int row = e >> 11, col = e & 2047;
      const float* src = (col < 1024) ? (inp + row * 1024 + col)
                                      : (hprev + row * 1024 + (col - 1024));
      v4f a = *(const v4f*)src, b = *(const v4f*)(src + 4);
      float vv[8] = {a.x, a.y, a.z, a.w, b.x, b.y, b.z, b.w};
      s8v hi, lo;
#pragma unroll
      for (int j = 0; j < 8; ++j) {
        u16 h = f2bf(vv[j]);
        hi[j] = (short)h;
        lo[j] = (short)f2bf(vv[j] - bf2f(h));
      }
      *(s8v*)(Ahi + e) = hi;
      *(s8v*)(Alo + e) = lo;
    } else {
      int e = (gi - GA) << 3; int n = e >> 11, k = e & 2047;
      const float* src;
      if (n < 4096) { int j = n >> 2, g = n & 3; src = wl + (size_t)((g << 10) | j) * 2048 + k; }
      else          { src = wlev + (size_t)(n - 4096) * 2048 + k; }
      v4f a = *(const v4f*)src, b = *(const v4f*)(src + 4);
      float vv[8] = {a.x, a.y, a.z, a.w, b.x, b.y, b.z, b.w};
      s8v hi, lo;
#pragma unroll
      for (int j = 0; j < 8; ++j) {
        u16 h = f2bf(vv[j]);
        hi[j] = (short)h;
        lo[j] = (short)f2bf(vv[j] - bf2f(h));
      }
      *(s8v*)(Whi + e) = hi;
      if (n >= 4096) *(s8v*)(Wlo + (size_t)(n - 4096) * 2048 + k) = lo;
    }
  }
}

// ----------------------------------------------- level GEMM (split-bf16) ---
__global__ __launch_bounds__(256) void k_gemm_level(
    const u16* __restrict__ Ahi, const u16* __restrict__ Alo,
    const u16* __restrict__ Whi, const u16* __restrict__ Wlo,
    float* __restrict__ part)
{
  __shared__ __align__(16) u16 smem[4 * 8192];
  u16 *Ah = smem, *Al = smem + 8192, *Bh = smem + 16384, *Bl = smem + 24576;
  const int tid = threadIdx.x, lane = tid & 63, wid = tid >> 6;
  const int wm = wid >> 1, wn = wid & 1;
  const int rm = blockIdx.x, s = blockIdx.y;
  const int lrow = lane >> 3, lcolE = (lane & 7) << 3;
  const int c16 = lane & 15, r16 = lane >> 4;
  f32x4 acc[4][4] = {};
  const u16* aBaseH = Ahi + (size_t)(rm << 7) * 2048;
  const u16* aBaseL = Alo + (size_t)(rm << 7) * 2048;
  const u16* bBaseH = Whi + (size_t)4096 * 2048;

  for (int kt = 0; kt < 4; ++kt) {
    const int k0 = (s << 8) + (kt << 6);
#pragma unroll
    for (int q = 0; q < 4; ++q) {
      const int ca = (wid << 2) + q;
      size_t roff = (size_t)((ca << 3) + lrow) * 2048 + k0 + lcolE;
      GLDS(aBaseH + roff, Ah + (ca << 9));
      GLDS(aBaseL + roff, Al + (ca << 9));
      GLDS(bBaseH + roff, Bh + (ca << 9));
      GLDS(Wlo + roff,    Bl + (ca << 9));
    }
    __syncthreads();
#pragma unroll
    for (int ks = 0; ks < 2; ++ks) {
      bf16x8 ah[4], al[4];
#pragma unroll
      for (int i = 0; i < 4; ++i) {
        int off = ((wm << 6) + (i << 4) + c16) * 64 + (ks << 5) + (r16 << 3);
        ah[i] = *(const bf16x8*)(Ah + off);
        al[i] = *(const bf16x8*)(Al + off);
      }
#pragma unroll
      for (int j = 0; j < 4; ++j) {
        int off = ((wn << 6) + (j << 4) + c16) * 64 + (ks << 5) + (r16 << 3);
        bf16x8 bh = *(const bf16x8*)(Bh + off);
        bf16x8 bl = *(const bf16x8*)(Bl + off);
#pragma unroll
        for (int i = 0; i < 4; ++i) {
          acc[i][j] = __builtin_amdgcn_mfma_f32_16x16x32_bf16(ah[i], bh, acc[i][j], 0, 0, 0);
          acc[i][j] = __builtin_amdgcn_mfma_f32_16x16x32_bf16(al[i], bh, acc[i][j], 0, 0, 0);
          acc[i][j] = __builtin_amdgcn_mfma_f32_16x16x32_bf16(ah[i], bl, acc[i][j], 0, 0, 0);
        }
      }
    }
    __syncthreads();
  }
#pragma unroll
  for (int mi = 0; mi < 4; ++mi)
#pragma unroll
    for (int ni = 0; ni < 4; ++ni)
#pragma unroll
      for (int r = 0; r < 4; ++r) {
        int ml = (wm << 6) + (mi << 4) + (r16 << 2) + r;
        int nl = (wn << 6) + (ni << 4) + c16;
        part[(size_t)((s << 13) + (rm << 7) + ml) * 128 + nl] = acc[mi][ni][r];
      }
}

// ------------------------------------------- softmax + cumsums (per row) ---
__global__ __launch_bounds__(256) void k_softmax(
    const float* __restrict__ part, float* __restrict__ ih, float* __restrict__ fh)
{
  const int tid = threadIdx.x, lane = tid & 63, w = tid >> 6;
  const int row = blockIdx.x * 4 + w;
  float vi = 0.f, vf = 0.f;
#pragma unroll
  for (int s = 0; s < 8; ++s) {
    vi += part[(size_t)((s << 13) + row) * 128 + lane];
    vf += part[(size_t)((s << 13) + row) * 128 + 64 + lane];
  }
  float mi = vi, mf = vf;
#pragma unroll
  for (int d = 1; d < 64; d <<= 1) {
    mi = fmaxf(mi, __shfl_xor(mi, d, 64));
    mf = fmaxf(mf, __shfl_xor(mf, d, 64));
  }
  float ei = __expf(vi - mi), ef = __expf(vf - mf);
  float si = ei, sf = ef;
#pragma unroll
  for (int d = 1; d < 64; d <<= 1) {
    si += __shfl_xor(si, d, 64);
    sf += __shfl_xor(sf, d, 64);
  }
  float pi = ei / si, pf = ef / sf;
  float ci = pi, cf = pf;
#pragma unroll
  for (int d = 1; d < 64; d <<= 1) {
    float t = __shfl_up(ci, d, 64); if (lane >= d) ci += t;
    float u = __shfl_up(cf, d, 64); if (lane >= d) cf += u;
  }
  ih[(row << 6) + lane] = 1.0f - (ci - pi);
  fh[(row << 6) + lane] = cf;
}

// -------------------------------------- main gates GEMM + fused epilogue ---
// 256x256 tile, 8-phase schedule (T2+T3+T4+T5). 512 threads = 8 waves (2Mx4N),
// per-wave 128x64 output. LDS: 4 slots x (A 256x32 + B 256x32) bf16 = 128 KB.
// Iteration t computes K-slices 4t..4t+3 (slot = slice&3), 2 phases per slice
// (i-half 0/1, 16 MFMA each). Stage phases (sp,h=0) stage slice 4t+3+sp into
// slot (sp+3)&3 (4 GLDS). vmcnt(8) every phase (never 0 in-loop); every read
// targets a slot staged >=5 phases earlier (covered by prev phase's vmcnt(8)
// + barrier); every overwrite is >=1 phase after the slot's last read
// (published by that phase's lgkmcnt(0) + barrier). LDS slot rows are 64 B;
// 16-B k-slots permuted by slot^=(row>>1)&3 -> 2-way bank access (free).
__global__ __launch_bounds__(512, 2) void k_gemm_main(
    const u16* __restrict__ Ab, const u16* __restrict__ Wb,
    const float* __restrict__ cprev, const float* __restrict__ ihp,
    const float* __restrict__ fhp, float* __restrict__ out)
{
  __shared__ __align__(16) u16 smem[65536];       // 128 KB
  const int tid = threadIdx.x, lane = tid & 63, wid = tid >> 6;
  const int wm = wid >> 2, wn = wid & 3;          // 2 x 4 wave grid
  const int c16 = lane & 15, r16 = lane >> 4;

  // bijective XCD swizzle (nwg=512, 512%8==0)
  const int bx = blockIdx.x;
  const int nb = (bx & 7) * 64 + (bx >> 3);
  const int rm = nb >> 4, cm = nb & 15;           // 32 row tiles x 16 col tiles

  // staging: thread -> (row sr, 16B slot slq); global src pre-permuted so the
  // linear GLDS dest (tid*16 within half) holds k-block slq^((sr>>1)&3).
  const int sr = tid >> 2;                         // 0..127
  const int slq = tid & 3;
  const int xk = (slq ^ ((sr >> 1) & 3)) << 3;
  const u16* pa = Ab + (size_t)(rm * 256 + sr) * 2048 + xk;
  const u16* pb = Wb + (size_t)(cm * 256 + sr) * 2048 + xk;
  char* const ldsA = (char*)smem + (wid << 10);
  char* const ldsB = (char*)smem + 65536 + (wid << 10);

  // ds_read: lane (c16,r16) reads row base + c16, k-slot r16 (swizzled).
  const int xsl = (r16 ^ ((c16 >> 1) & 3)) << 3;
  const int base_a = (wm * 128 + c16) * 32 + xsl;  // + ii*512 per M-frag
  const int base_b = (wn * 64 + c16) * 32 + xsl;   // + j*512 per N-frag

  f32x4 acc[8][4] = {};
  bf16x8 bS[4];

#define STAGE4(slice, slot) do {                                       \
    const u16* sa_ = pa + (slice) * 32;                                \
    const u16* sb_ = pb + (slice) * 32;                                \
    char* da_ = ldsA + (slot) * 16384;                                 \
    char* db_ = ldsB + (slot) * 16384;                                 \
    GLDS(sa_, da_); GLDS(sa_ + 262144, da_ + 8192);                    \
    GLDS(sb_, db_); GLDS(sb_ + 262144, db_ + 8192);                    \
  } while (0)

  // prologue: slices 0,1,2 -> slots 0,1,2; wait slot 0 complete, publish.
  STAGE4(0, 0); STAGE4(1, 1); STAGE4(2, 2);
  asm volatile("s_waitcnt vmcnt(8)" ::: "memory");
  __builtin_amdgcn_s_barrier();

  for (int t = 0; t < 16; ++t) {
#define PHASE(sp, h) do {                                              \
    asm volatile("s_waitcnt vmcnt(8)" ::: "memory");                   \
    bf16x8 aX[4];                                                      \
    _Pragma("unroll")                                                  \
    for (int i = 0; i < 4; ++i)                                        \
      aX[i] = *(const bf16x8*)(smem + (sp) * 8192 + base_a + ((h) * 4 + i) * 512); \
    if ((h) == 0) {                                                    \
      _Pragma("unroll")                                                \
      for (int j = 0; j < 4; ++j)                                      \
        bS[j] = *(const bf16x8*)(smem + 32768 + (sp) * 8192 + base_b + j * 512); \
      STAGE4((4 * t + 3 + (sp)) & 63, ((sp) + 3) & 3);                 \
    }                                                                  \
    __builtin_amdgcn_s_barrier();                                      \
    asm volatile("s_waitcnt lgkmcnt(0)" ::: "memory");                 \
    __builtin_amdgcn_s_setprio(1);                                     \
    _Pragma("unroll")                                                  \
    for (int i = 0; i < 4; ++i)                                        \
      _Pragma("unroll")                                                \
      for (int j = 0; j < 4; ++j)                                      \
        acc[(h) * 4 + i][j] = __builtin_amdgcn_mfma_f32_16x16x32_bf16( \
            aX[i], bS[j], acc[(h) * 4 + i][j], 0, 0, 0);               \
    __builtin_amdgcn_s_setprio(0);                                     \
    __builtin_amdgcn_s_barrier();                                      \
  } while (0)
    PHASE(0, 0); PHASE(0, 1);
    PHASE(1, 0); PHASE(1, 1);
    PHASE(2, 0); PHASE(2, 1);
    PHASE(3, 0); PHASE(3, 1);
#undef PHASE
  }
#undef STAGE4

  // drain dummy tail stages before LDS reuse
  asm volatile("s_waitcnt vmcnt(0)" ::: "memory");
  __builtin_amdgcn_s_barrier();

  // ---- fused ON-LSTM epilogue: 4 passes (one per wn), epi = f32[256][64] ----
  float* epi = (float*)smem;
  for (int p = 0; p < 4; ++p) {
    if (wn == p) {
#pragma unroll
      for (int i = 0; i < 8; ++i)
#pragma unroll
        for (int j = 0; j < 4; ++j)
#pragma unroll
          for (int r = 0; r < 4; ++r) {
            int rowl = wm * 128 + i * 16 + r16 * 4 + r;
            int coll = j * 16 + c16;
            float v = acc[i][j][r];
            v = ((c16 & 3) == 3) ? ftanhf(v) : fsig(v);
            epi[rowl * 64 + coll] = v;
          }
    }
    __syncthreads();
#pragma unroll
    for (int e = 0; e < 8; ++e) {
      int idx = (e << 9) + tid;
      int m = idx >> 4, jl = idx & 15;
      v4f v = *(const v4f*)(epi + m * 64 + (jl << 2));   // i,f,o,g (activated)
      int rowg = rm * 256 + m;
      int jg = cm * 64 + p * 16 + jl;                    // hidden index
      float cp = cprev[rowg * 1024 + jg];
      int lv = jg >> 4;
      float vih = ihp[(rowg << 6) + lv], vfh = fhp[(rowg << 6) + lv];
      float iv = v.x, fv = v.y, ov = v.z, gv = v.w;
      float wq = vih * vfh;
      float c = wq * (fv * cp + iv * gv) + (vfh - wq) * cp + (vih - wq) * gv;
      float h = ov * ftanhf(c);
      out[rowg * 1024 + jg] = h;
      out[8388608 + rowg * 1024 + jg] = c;
    }
    __syncthreads();
  }
}

// -------------------------------------------------------------- launcher ---
extern "C" void kernel_launch(void* const* d_in, const int* in_sizes, int n_in,
                              void* d_out, int out_size, void* d_ws, size_t ws_size,
                              hipStream_t stream) {
  (void)in_sizes; (void)n_in; (void)out_size; (void)ws_size;
  const float* inp   = (const float*)d_in[0];
  const float* hprev = (const float*)d_in[1];
  const float* cprev = (const float*)d_in[2];
  const float* wl    = (const float*)d_in[3];
  const float* wlev  = (const float*)d_in[4];
  float* out = (float*)d_out;
  char* ws = (char*)d_ws;

  u16* Ahi  = (u16*)(ws);
  u16* Alo  = (u16*)(ws + 33554432);
  u16* Whi  = (u16*)(ws + 67108864);
  u16* Wlo  = (u16*)(ws + 84410368);
  float* part = (float*)(ws + 84934656);
  float* ih   = (float*)(ws + 118489088);
  float* fh   = (float*)(ws + 120586240);

  k_convert<<<dim3(2048), dim3(256), 0, stream>>>(inp, hprev, wl, wlev, Ahi, Alo, Whi, Wlo);
  k_gemm_level<<<dim3(64, 8), dim3(256), 0, stream>>>(Ahi, Alo, Whi, Wlo, part);
  k_softmax<<<dim3(2048), dim3(256), 0, stream>>>(part, ih, fh);
  k_gemm_main<<<dim3(512), dim3(512), 0, stream>>>(Ahi, Whi, cprev, ih, fh, out);
}